// Round 16
// baseline (341.517 us; speedup 1.0000x reference)
//
#include <hip/hip_runtime.h>

typedef unsigned short u16;
typedef __attribute__((ext_vector_type(8))) short bf16x8;
typedef __attribute__((ext_vector_type(4))) float f32x4;
typedef __attribute__((ext_vector_type(16))) float f32x16;
typedef __attribute__((ext_vector_type(4))) unsigned short u16x4;

__device__ __forceinline__ u16 f2b(float f) {
  union { float f; unsigned u; } x; x.f = f;
  unsigned u = x.u;
  return (u16)((u + 0x7fffu + ((u >> 16) & 1u)) >> 16);
}
__device__ __forceinline__ float b2f(u16 b) {
  union { unsigned u; float f; } x; x.u = ((unsigned)b) << 16;
  return x.f;
}

// async global->LDS, 16B per lane; lds base must be wave-uniform.
__device__ __forceinline__ void gload_lds16(const void* g, void* l) {
  __builtin_amdgcn_global_load_lds(
      (const __attribute__((address_space(1))) void*)g,
      (__attribute__((address_space(3))) void*)l, 16, 0, 0);
}

// ---------------- fused prep ----------------
// [0,768): W_attn->WaT; [768,1792): x->xT AND x->xb (one pass);
// [1792,5888): WcombT (LDS-transposed W_fuse); [5888,7936): conv_h.
__device__ __forceinline__ void tr_f2b_body(const float* __restrict__ in,
                                            u16* __restrict__ out, int R, int C,
                                            int bx, int by, int t, float* tile) {
  int r0 = by * 64, c0 = bx * 64;
  for (int ch = t; ch < 1024; ch += 256) {
    int r = ch >> 4, q = ch & 15;
    float4 v = *(const float4*)(in + (long)(r0 + r) * C + c0 + q * 4);
    tile[r * 65 + q * 4 + 0] = v.x; tile[r * 65 + q * 4 + 1] = v.y;
    tile[r * 65 + q * 4 + 2] = v.z; tile[r * 65 + q * 4 + 3] = v.w;
  }
  __syncthreads();
  for (int ch = t; ch < 1024; ch += 256) {
    int cc = ch >> 4, g = ch & 15;
    u16x4 o;
    o[0] = f2b(tile[(g * 4 + 0) * 65 + cc]); o[1] = f2b(tile[(g * 4 + 1) * 65 + cc]);
    o[2] = f2b(tile[(g * 4 + 2) * 65 + cc]); o[3] = f2b(tile[(g * 4 + 3) * 65 + cc]);
    *(u16x4*)(out + (long)(c0 + cc) * R + r0 + g * 4) = o;
  }
}

__global__ void prep_k(const float* __restrict__ x, const float* __restrict__ W_attn,
                       const float* __restrict__ W_fuse, const float* __restrict__ W_proj,
                       const float* __restrict__ alpha,
                       u16* __restrict__ xb, u16* __restrict__ WaT, u16* __restrict__ xT,
                       u16* __restrict__ WcombT, float* __restrict__ hbuf) {
  __shared__ float smem[64 * 65];
  const int id = blockIdx.x, t = threadIdx.x;
  if (id < 768) {                        // W_attn[1024][3072] -> WaT[3072][1024]
    tr_f2b_body(W_attn, WaT, 1024, 3072, id % 48, id / 48, t, smem);
  } else if (id < 1792) {                // x -> xT (transpose) AND xb (cvt), one pass
    int local = id - 768;
    int bx = local & 15, by = (local >> 4) & 31, z = local >> 9;
    const float* src = x + (long)z * 2048 * 1024;
    u16* xbz = xb + (long)z * 2048 * 1024;
    u16* xTz = xT + (long)z * 1024 * 2048;
    int r0 = by * 64, c0 = bx * 64;
    for (int ch = t; ch < 1024; ch += 256) {
      int r = ch >> 4, q = ch & 15;
      float4 v = *(const float4*)(src + (long)(r0 + r) * 1024 + c0 + q * 4);
      smem[r * 65 + q * 4 + 0] = v.x; smem[r * 65 + q * 4 + 1] = v.y;
      smem[r * 65 + q * 4 + 2] = v.z; smem[r * 65 + q * 4 + 3] = v.w;
      u16x4 o;
      o[0] = f2b(v.x); o[1] = f2b(v.y); o[2] = f2b(v.z); o[3] = f2b(v.w);
      *(u16x4*)(xbz + (long)(r0 + r) * 1024 + c0 + q * 4) = o;
    }
    __syncthreads();
    for (int ch = t; ch < 1024; ch += 256) {
      int cc = ch >> 4, g = ch & 15;
      u16x4 o;
      o[0] = f2b(smem[(g * 4 + 0) * 65 + cc]); o[1] = f2b(smem[(g * 4 + 1) * 65 + cc]);
      o[2] = f2b(smem[(g * 4 + 2) * 65 + cc]); o[3] = f2b(smem[(g * 4 + 3) * 65 + cc]);
      *(u16x4*)(xTz + (long)(c0 + cc) * 2048 + r0 + g * 4) = o;
    }
  } else if (id < 5888) {                // WcombT[c][hd0] = sum_d1 Wf[d0][d1] Wp[h*64+d1][c]
    float* wfT = smem;                   // [64][65] transposed W_fuse top half
    for (int ch = t; ch < 4096; ch += 256) {
      int d0 = ch >> 6, d1 = ch & 63;
      wfT[d1 * 65 + d0] = W_fuse[ch];
    }
    __syncthreads();
    long idx = (long)(id - 1792) * 256 + t;
    int c = (int)(idx >> 10), hd0 = (int)(idx & 1023);
    int h = hd0 >> 6, d0 = hd0 & 63;
    float acc = 0.f;
    for (int d1 = 0; d1 < 64; ++d1)
      acc += wfT[d1 * 65 + d0] * W_proj[(long)(h * 64 + d1) * 1024 + c];
    WcombT[(long)c * 1024 + hd0] = f2b(acc);
  } else {                               // conv_h: h = irfft(exp(-j*alpha), n=2048)
    int tt = id - 5888;
    float a = alpha[0];
    const float wph = 3.14159265358979323846f / 1024.f;
    float acc = 0.f;
    for (int j = 1 + t; j < 1024; j += 256) {
      int ph = (j * tt) & 2047;
      acc += 2.f * __expf(-a * (float)j) * __cosf((float)ph * wph);
    }
    if (t == 0) {
      acc += 1.0f;
      int ph = (1024 * tt) & 2047;
      acc += __expf(-a * 1024.f) * __cosf((float)ph * wph);
    }
    float* red = smem;
    red[t] = acc;
    __syncthreads();
    for (int s = 128; s > 0; s >>= 1) {
      if (t < s) red[t] += red[t + s];
      __syncthreads();
    }
    if (t == 0) hbuf[tt] = red[0] * (1.f / 2048.f);
  }
}

// ---------------- Hb fill ----------------
__global__ void hb_k(const float* __restrict__ hbuf, u16* __restrict__ Hb) {
  long idx0 = ((long)blockIdx.x * 256 + threadIdx.x) * 16;
  int tt = (int)(idx0 >> 11), u0 = (int)(idx0 & 2047);
  u16x4 o;
#pragma unroll
  for (int g = 0; g < 4; ++g) {
#pragma unroll
    for (int e = 0; e < 4; ++e)
      o[e] = f2b(hbuf[(tt - (u0 + g * 4 + e)) & 2047]);
    *(u16x4*)(Hb + idx0 + g * 4) = o;
  }
}

// ---------------- shared bf16 MFMA GEMM body (32x32x16): C = A[M,K] @ Bt[N,K]^T ----------------
// 128x128 tile, BK=64, 4 waves, global_load_lds staging, swizzled LDS.
// C/D: col = lane&31, row = (reg&3) + 8*(reg>>2) + 4*(lane>>5)  [m74/m101-verified]
// bias_mode: 0 none, 1 bias[col], 2 bias[(row>>11)*ldc+col], 3 bias[row]
__device__ __forceinline__ void gemm_body(
    const u16* __restrict__ Ab, int lda, const u16* __restrict__ Bb, int ldb,
    void* __restrict__ Cv, long coff, int ldc, int K, int m0, int n0,
    int bias_mode, const float* __restrict__ bias, bool out_f32,
    u16* As, u16* Bs) {
  const int t = threadIdx.x;
  const int w = t >> 6, l = t & 63;
  const int wr = (w >> 1) * 64, wc = (w & 1) * 64;
  const int lr32 = l & 31, lh = l >> 5;

  f32x16 acc[2][2] = {};

  for (int k0 = 0; k0 < K; k0 += 64) {
    __syncthreads();
#pragma unroll
    for (int q = 0; q < 4; ++q) {
      int ch = (w * 4 + q) * 64 + l;       // linear 16B-chunk index
      int row = ch >> 3;
      int cg = (ch & 7) ^ (row & 7);       // inverse-swizzled source column
      gload_lds16(Ab + (long)(m0 + row) * lda + k0 + cg * 8, &As[(w * 4 + q) * 512]);
      gload_lds16(Bb + (long)(n0 + row) * ldb + k0 + cg * 8, &Bs[(w * 4 + q) * 512]);
    }
    __syncthreads();
#pragma unroll
    for (int kk = 0; kk < 4; ++kk) {       // 4 K-substeps of 16
      bf16x8 af[2], bfr[2];
#pragma unroll
      for (int i = 0; i < 2; ++i) {
        int ar = wr + i * 32 + lr32;
        af[i] = *(const bf16x8*)&As[ar * 64 + ((((kk << 1) | lh) ^ (ar & 7)) << 3)];
        int br = wc + i * 32 + lr32;
        bfr[i] = *(const bf16x8*)&Bs[br * 64 + ((((kk << 1) | lh) ^ (br & 7)) << 3)];
      }
#pragma unroll
      for (int i = 0; i < 2; ++i)
#pragma unroll
        for (int j = 0; j < 2; ++j)
          acc[i][j] = __builtin_amdgcn_mfma_f32_32x32x16_bf16(af[i], bfr[j], acc[i][j], 0, 0, 0);
    }
  }

#pragma unroll
  for (int i = 0; i < 2; ++i)
#pragma unroll
    for (int j = 0; j < 2; ++j)
#pragma unroll
      for (int reg = 0; reg < 16; ++reg) {
        int row = m0 + wr + i * 32 + (reg & 3) + 8 * (reg >> 2) + 4 * lh;
        int col = n0 + wc + j * 32 + lr32;
        float v = acc[i][j][reg];
        if (bias_mode == 1) v += bias[col];
        else if (bias_mode == 2) v += bias[(row >> 11) * ldc + col];
        else if (bias_mode == 3) v += bias[row];
        if (out_f32)
          ((float*)Cv)[coff + (long)row * ldc + col] = v;
        else
          ((u16*)Cv)[coff + (long)row * ldc + col] = f2b(v);
      }
}

// phase 1: Gx (xm = Hb @ x[b], ids [0,256)) + vT (Wv @ xb[b]^T, ids [256,512))
__global__ __launch_bounds__(256)
void phase1_k(const u16* __restrict__ Hb, const u16* __restrict__ xT,
              const u16* __restrict__ xb, const u16* __restrict__ WaT,
              const float* __restrict__ b_attn,
              u16* __restrict__ xm, u16* __restrict__ vT) {
  __shared__ u16 As[128 * 64];
  __shared__ u16 Bs[128 * 64];
  const int id = blockIdx.x;
  if (id < 256) {   // Gx: xm[z][tt][c] = sum_u Hb[tt][u] x[z][u][c]
    int z = id >> 7, r = id & 127;           // 16 m-tiles x 8 n-tiles
    gemm_body(Hb, 2048, xT + (long)z * 1024 * 2048, 2048,
              (void*)xm, (long)z * 2048 * 1024, 1024, 2048,
              (r >> 3) * 128, (r & 7) * 128, 0, nullptr, false, As, Bs);
  } else {          // vT[z][c][t] = sum_k Wv[c][k] xb[z][t][k] + b_v[c]
    int id2 = id - 256;
    int z = id2 >> 7, r = id2 & 127;         // 8 m-tiles x 16 n-tiles
    gemm_body(WaT + (long)2048 * 1024, 1024, xb + (long)z * 2048 * 1024, 1024,
              (void*)vT, (long)z * 1024 * 2048, 2048, 1024,
              (r >> 4) * 128, (r & 15) * 128, 3, b_attn + 2048, false, As, Bs);
  }
}

// G1b: qkm2 = xm @ W_qk + b_qk  (grid (16,33); y==32 row does vT row-sums)
__global__ __launch_bounds__(256)
void g1b_k(const u16* __restrict__ xm, const u16* __restrict__ WaT,
           const float* __restrict__ b_attn, const u16* __restrict__ vT,
           u16* __restrict__ qkm2, float* __restrict__ part) {
  __shared__ u16 As[128 * 64];
  __shared__ u16 Bs[128 * 64];
  if (blockIdx.y == 32) {    // vmean partial: full row sums of vT (rows = b*1024+c)
    int row = blockIdx.x * 128 + (threadIdx.x >> 1);
    int half = threadIdx.x & 1;
    const bf16x8* src = (const bf16x8*)(vT + (long)row * 2048 + half * 1024);
    float s = 0.f;
    for (int i = 0; i < 128; ++i) {
      bf16x8 v = src[i];
#pragma unroll
      for (int k = 0; k < 8; ++k) s += b2f((u16)(unsigned short)v[k]);
    }
    s += __shfl_xor(s, 1);
    if (half == 0) part[row] = s;
    return;
  }
  gemm_body(xm, 1024, WaT, 1024, (void*)qkm2, 0L, 2048, 1024,
            blockIdx.y * 128, blockIdx.x * 128, 1, b_attn, false, As, Bs);
}

// G3: out = localf @ WcombT^T + out_const[b]
__global__ __launch_bounds__(256)
void g3_k(const u16* __restrict__ localf, const u16* __restrict__ WcombT,
          const float* __restrict__ out_const, float* __restrict__ out) {
  __shared__ u16 As[128 * 64];
  __shared__ u16 Bs[128 * 64];
  gemm_body(localf, 1024, WcombT, 1024, (void*)out, 0L, 1024, 1024,
            blockIdx.y * 128, blockIdx.x * 128, 2, out_const, true, As, Bs);
}

// ---------------- latent chain (standalone): mean->W_lat->W_fuse[64:]->W_proj ----------------
__global__ void latent_k(const float* __restrict__ part, const float* __restrict__ W_lat,
                         const float* __restrict__ b_lat, const float* __restrict__ W_fuse,
                         const float* __restrict__ b_fuse, const float* __restrict__ W_proj,
                         const float* __restrict__ b_proj, float* __restrict__ out_const) {
  const int b = blockIdx.x, t = threadIdx.x;
  const int h = t >> 6, d = t & 63;
  __shared__ float mv[1024], lat[1024];
  mv[t] = part[(long)b * 1024 + t] * (1.f / 2048.f);
  __syncthreads();
  float acc = b_lat[d];
  for (int k = 0; k < 64; ++k) acc += mv[h * 64 + k] * W_lat[k * 64 + d];
  lat[t] = acc;
  __syncthreads();
  float acc2 = b_fuse[d];
  for (int k = 0; k < 64; ++k) acc2 += lat[h * 64 + k] * W_fuse[(64 + k) * 64 + d];
  __syncthreads();
  mv[t] = acc2;                           // lat_term
  __syncthreads();
  float acc3 = b_proj[t];
  for (int hd = 0; hd < 1024; ++hd) acc3 += mv[hd] * W_proj[(long)hd * 1024 + t];
  out_const[b * 1024 + t] = acc3;
}

// ---------------- flash attention: swapped QK^T (S^T in regs) ----------------
// grid (B, H, T/128); 256 thr, 4 waves; each wave owns 32 Q rows.
// sa[i][j] = mfma(kf[j], qf[i][kk]): lane holds S[k=j*16+lk*4+r][q=i*16+lrow]
// -> rel loads become float4 (k-contiguous), P stores become 8B packed.
// rel added unconditionally (exact when zero). PV and output layout unchanged.
__global__ __launch_bounds__(256)
void fa_k(const u16* __restrict__ qkm2, const u16* __restrict__ vT,
          const float* __restrict__ rel, u16* __restrict__ localf) {
  const int b = blockIdx.x, h = blockIdx.y;
  const int t0 = blockIdx.z * 128;
  const int t = threadIdx.x, w = t >> 6, l = t & 63;
  const int lrow = l & 15, lk = l >> 4;
  __shared__ u16 QPs[9216];      // Q staging (8192 u16), then per-wave P [32][72]
  __shared__ u16 Ks[2][64 * 64];
  __shared__ u16 Vs[2][64 * 64];

  const u16* qm = qkm2 + (long)b * 2048 * 2048;
  const u16* km = qm + 1024;
  // swapped layout: lane's q-row = t0+w*32+i*16+lrow, k-cols = it*64+j*16+lk*4..+3
  const float* relp = rel + ((long)h * 2048 + t0 + w * 32 + lrow) * 2048 + lk * 4;

#pragma unroll
  for (int q = 0; q < 4; ++q) {
    int ch = (w * 4 + q) * 64 + l;
    int r = ch >> 3;
    int cg = (ch & 7) ^ (r & 7);
    gload_lds16(qm + (long)(t0 + r) * 2048 + h * 64 + cg * 8, &QPs[(w * 4 + q) * 512]);
  }
  auto stage = [&](int tile, int buf) {
    int s0 = tile * 64;
#pragma unroll
    for (int q = 0; q < 2; ++q) {
      int ch = (w * 2 + q) * 64 + l;
      int r = ch >> 3;
      int cg = (ch & 7) ^ (r & 7);
      gload_lds16(km + (long)(s0 + r) * 2048 + h * 64 + cg * 8,
                  &Ks[buf][(w * 2 + q) * 512]);
      gload_lds16(vT + ((long)b * 1024 + h * 64 + r) * 2048 + s0 + cg * 8,
                  &Vs[buf][(w * 2 + q) * 512]);
    }
  };
  stage(0, 0);
  __syncthreads();

  bf16x8 qf[2][2];
#pragma unroll
  for (int i = 0; i < 2; ++i)
#pragma unroll
    for (int kk = 0; kk < 2; ++kk) {
      int r = w * 32 + i * 16 + lrow;
      qf[i][kk] = *(const bf16x8*)&QPs[r * 64 + ((((kk << 2) | lk) ^ (r & 7)) << 3)];
    }
  __syncthreads();  // all waves done reading Q before any P store into QPs

  // P tile per wave: [32 q][72 u16] (144B rows, 16B-aligned)
  u16* Pw = QPs + w * 2304 + lrow * 72 + lk * 4;         // + i*1152 + j*16 (8B store)
  const u16* Pr = QPs + w * 2304 + lrow * 72 + lk * 8;   // read base (+i*1152+kk*32)

  f32x4 o[2][4] = {};
  float lsum[2] = {0.f, 0.f};

  for (int it = 0; it < 32; ++it) {
    const int cur = it & 1;
    const u16* Kb = Ks[cur];
    const u16* Vb = Vs[cur];

    // QK^T, swapped: A-operand = K, B-operand = Q
    f32x4 sa[2][4] = {};
#pragma unroll
    for (int kk = 0; kk < 2; ++kk) {
      bf16x8 kf[4];
#pragma unroll
      for (int j = 0; j < 4; ++j) {
        int r = j * 16 + lrow;
        kf[j] = *(const bf16x8*)&Kb[r * 64 + ((((kk << 2) | lk) ^ (r & 7)) << 3)];
      }
#pragma unroll
      for (int i = 0; i < 2; ++i)
#pragma unroll
        for (int j = 0; j < 4; ++j)
          sa[i][j] = __builtin_amdgcn_mfma_f32_16x16x32_bf16(kf[j], qf[i][kk], sa[i][j], 0, 0, 0);
    }

    if (it < 31) stage(it + 1, cur ^ 1);   // K/V prefetch (async -> LDS)

    // rel (float4, k-contiguous) + exp + packed P store
#pragma unroll
    for (int i = 0; i < 2; ++i)
#pragma unroll
      for (int j = 0; j < 4; ++j) {
        f32x4 rv = *(const f32x4*)(relp + (long)i * 32768 + it * 64 + j * 16);
        u16x4 pk;
        float ps = 0.f;
#pragma unroll
        for (int r = 0; r < 4; ++r) {
          float vv = sa[i][j][r] * 0.1803368867f      // 0.125 * log2(e)
                     + 1.4426950409f * rv[r];
          float p = exp2f(fminf(vv, 86.0f));
          ps += p;
          pk[r] = f2b(p);
        }
        lsum[i] += ps;
        *(u16x4*)(Pw + i * 1152 + j * 16) = pk;
      }

    // PV (standard operand order; P rows = q, V rows = d)
#pragma unroll
    for (int kk = 0; kk < 2; ++kk) {
      bf16x8 pf[2], vf[4];
#pragma unroll
      for (int i = 0; i < 2; ++i)
        pf[i] = *(const bf16x8*)&Pr[i * 1152 + kk * 32];
#pragma unroll
      for (int j = 0; j < 4; ++j) {
        int r = j * 16 + lrow;
        vf[j] = *(const bf16x8*)&Vb[r * 64 + ((((kk << 2) | lk) ^ (r & 7)) << 3)];
      }
#pragma unroll
      for (int i = 0; i < 2; ++i)
#pragma unroll
        for (int j = 0; j < 4; ++j)
          o[i][j] = __builtin_amdgcn_mfma_f32_16x16x32_bf16(pf[i], vf[j], o[i][j], 0, 0, 0);
    }
    __syncthreads();
  }

  // denominators: lane holds partial for q=i*16+lrow over its k-subset (fixed lk);
  // total = reduce across lk groups (xor 16, 32); then redistribute to PV layout
  // (output row q = i*16 + lk*4 + r -> source lane lrow = lk*4+r).
  float sred[2];
#pragma unroll
  for (int i = 0; i < 2; ++i) {
    float s = lsum[i];
    s += __shfl_xor(s, 16);
    s += __shfl_xor(s, 32);
    sred[i] = s;
  }
#pragma unroll
  for (int i = 0; i < 2; ++i)
#pragma unroll
    for (int r = 0; r < 4; ++r) {
      float denom = __shfl(sred[i], lk * 4 + r);
      float inv = 1.0f / denom;
#pragma unroll
      for (int j = 0; j < 4; ++j)
        localf[((long)b * 2048 + t0 + w * 32 + i * 16 + lk * 4 + r) * 1024
               + h * 64 + j * 16 + lrow] = f2b(o[i][j][r] * inv);
    }
}

// ---------------- launch ----------------
extern "C" void kernel_launch(void* const* d_in, const int* in_sizes, int n_in,
                              void* d_out, int out_size, void* d_ws, size_t ws_size,
                              hipStream_t stream) {
  (void)in_sizes; (void)n_in; (void)out_size; (void)ws_size;
  const float* x      = (const float*)d_in[0];
  const float* W_attn = (const float*)d_in[1];
  const float* b_attn = (const float*)d_in[2];
  const float* W_proj = (const float*)d_in[3];
  const float* b_proj = (const float*)d_in[4];
  const float* rel    = (const float*)d_in[5];
  const float* alpha  = (const float*)d_in[6];
  const float* W_lat  = (const float*)d_in[7];
  const float* b_lat  = (const float*)d_in[8];
  const float* W_fuse = (const float*)d_in[9];
  const float* b_fuse = (const float*)d_in[10];
  float* out = (float*)d_out;
  char* ws = (char*)d_ws;
  const size_t MiB = 1048576;

  u16*   xb       = (u16*)(ws + 0 * MiB);    // [4096][1024] bf16
  u16*   xT       = (u16*)(ws + 8 * MiB);    // [2][1024][2048] bf16
  u16*   WaT      = (u16*)(ws + 16 * MiB);   // [3072][1024] bf16
  u16*   Hb       = (u16*)(ws + 22 * MiB);   // [2048][2048] bf16
  u16*   xm       = (u16*)(ws + 30 * MiB);   // [2][2048][1024] bf16 (= H x)
  u16*   qkm2     = (u16*)(ws + 46 * MiB);   // [4096][2048] bf16 (q|k modulated)
  u16*   vT       = (u16*)(ws + 62 * MiB);   // [2][1024][2048] bf16
  u16*   localf   = (u16*)(ws + 70 * MiB);   // [4096][1024] bf16
  u16*   WcombT   = (u16*)(ws + 78 * MiB);   // [1024][1024] bf16
  float* hbuf     = (float*)(ws + 80 * MiB);
  float* out_const= (float*)(ws + 80 * MiB + 16384);
  float* part     = (float*)(ws + 80 * MiB + 65536);  // [2048] f32 row sums

  // 1. prep: WaT, xT+xb (one pass over x), WcombT (gather-fixed), conv_h
  prep_k<<<7936, 256, 0, stream>>>(x, W_attn, W_fuse, W_proj, alpha,
                                   xb, WaT, xT, WcombT, hbuf);
  // 2. Hb fill
  hb_k<<<1024, 256, 0, stream>>>(hbuf, Hb);

  // 3. phase1: Gx (xm) + vT GEMMs, 512 blocks
  phase1_k<<<512, 256, 0, stream>>>(Hb, xT, xb, WaT, b_attn, xm, vT);

  // 4. G1b: qkm2 = xm @ W_qk + b_qk; plus vT row-sum partials (y==32)
  g1b_k<<<dim3(16, 33), 256, 0, stream>>>(xm, WaT, b_attn, vT, qkm2, part);

  // 5. latent chain -> out_const
  latent_k<<<2, 1024, 0, stream>>>(part, W_lat, b_lat, W_fuse, b_fuse,
                                   W_proj, b_proj, out_const);

  // 6. flash attention (swapped QK^T, vectorized rel) -> localf
  fa_k<<<dim3(2, 16, 16), 256, 0, stream>>>(qkm2, vT, rel, localf);

  // 7. G3: out = localf @ WcombT^T + out_const[b]
  g3_k<<<dim3(8, 32), 256, 0, stream>>>(localf, WcombT, out_const, out);
}

// Round 17
// 288.463 us; speedup vs baseline: 1.1839x; 1.1839x over previous
//
#include <hip/hip_runtime.h>

typedef unsigned short u16;
typedef __attribute__((ext_vector_type(8))) short bf16x8;
typedef __attribute__((ext_vector_type(4))) float f32x4;
typedef __attribute__((ext_vector_type(16))) float f32x16;
typedef __attribute__((ext_vector_type(4))) unsigned short u16x4;

__device__ __forceinline__ u16 f2b(float f) {
  union { float f; unsigned u; } x; x.f = f;
  unsigned u = x.u;
  return (u16)((u + 0x7fffu + ((u >> 16) & 1u)) >> 16);
}
__device__ __forceinline__ float b2f(u16 b) {
  union { unsigned u; float f; } x; x.u = ((unsigned)b) << 16;
  return x.f;
}

// async global->LDS, 16B per lane; lds base must be wave-uniform.
__device__ __forceinline__ void gload_lds16(const void* g, void* l) {
  __builtin_amdgcn_global_load_lds(
      (const __attribute__((address_space(1))) void*)g,
      (__attribute__((address_space(3))) void*)l, 16, 0, 0);
}

// ---------------- fused prep ----------------
// [0,768): W_attn->WaT; [768,1792): x->xT AND x->xb (one pass);
// [1792,5888): WcombT (LDS-transposed W_fuse); [5888,7936): conv_h.
__device__ __forceinline__ void tr_f2b_body(const float* __restrict__ in,
                                            u16* __restrict__ out, int R, int C,
                                            int bx, int by, int t, float* tile) {
  int r0 = by * 64, c0 = bx * 64;
  for (int ch = t; ch < 1024; ch += 256) {
    int r = ch >> 4, q = ch & 15;
    float4 v = *(const float4*)(in + (long)(r0 + r) * C + c0 + q * 4);
    tile[r * 65 + q * 4 + 0] = v.x; tile[r * 65 + q * 4 + 1] = v.y;
    tile[r * 65 + q * 4 + 2] = v.z; tile[r * 65 + q * 4 + 3] = v.w;
  }
  __syncthreads();
  for (int ch = t; ch < 1024; ch += 256) {
    int cc = ch >> 4, g = ch & 15;
    u16x4 o;
    o[0] = f2b(tile[(g * 4 + 0) * 65 + cc]); o[1] = f2b(tile[(g * 4 + 1) * 65 + cc]);
    o[2] = f2b(tile[(g * 4 + 2) * 65 + cc]); o[3] = f2b(tile[(g * 4 + 3) * 65 + cc]);
    *(u16x4*)(out + (long)(c0 + cc) * R + r0 + g * 4) = o;
  }
}

__global__ void prep_k(const float* __restrict__ x, const float* __restrict__ W_attn,
                       const float* __restrict__ W_fuse, const float* __restrict__ W_proj,
                       const float* __restrict__ alpha,
                       u16* __restrict__ xb, u16* __restrict__ WaT, u16* __restrict__ xT,
                       u16* __restrict__ WcombT, float* __restrict__ hbuf) {
  __shared__ float smem[64 * 65];
  const int id = blockIdx.x, t = threadIdx.x;
  if (id < 768) {                        // W_attn[1024][3072] -> WaT[3072][1024]
    tr_f2b_body(W_attn, WaT, 1024, 3072, id % 48, id / 48, t, smem);
  } else if (id < 1792) {                // x -> xT (transpose) AND xb (cvt), one pass
    int local = id - 768;
    int bx = local & 15, by = (local >> 4) & 31, z = local >> 9;
    const float* src = x + (long)z * 2048 * 1024;
    u16* xbz = xb + (long)z * 2048 * 1024;
    u16* xTz = xT + (long)z * 1024 * 2048;
    int r0 = by * 64, c0 = bx * 64;
    for (int ch = t; ch < 1024; ch += 256) {
      int r = ch >> 4, q = ch & 15;
      float4 v = *(const float4*)(src + (long)(r0 + r) * 1024 + c0 + q * 4);
      smem[r * 65 + q * 4 + 0] = v.x; smem[r * 65 + q * 4 + 1] = v.y;
      smem[r * 65 + q * 4 + 2] = v.z; smem[r * 65 + q * 4 + 3] = v.w;
      u16x4 o;
      o[0] = f2b(v.x); o[1] = f2b(v.y); o[2] = f2b(v.z); o[3] = f2b(v.w);
      *(u16x4*)(xbz + (long)(r0 + r) * 1024 + c0 + q * 4) = o;
    }
    __syncthreads();
    for (int ch = t; ch < 1024; ch += 256) {
      int cc = ch >> 4, g = ch & 15;
      u16x4 o;
      o[0] = f2b(smem[(g * 4 + 0) * 65 + cc]); o[1] = f2b(smem[(g * 4 + 1) * 65 + cc]);
      o[2] = f2b(smem[(g * 4 + 2) * 65 + cc]); o[3] = f2b(smem[(g * 4 + 3) * 65 + cc]);
      *(u16x4*)(xTz + (long)(c0 + cc) * 2048 + r0 + g * 4) = o;
    }
  } else if (id < 5888) {                // WcombT[c][hd0] = sum_d1 Wf[d0][d1] Wp[h*64+d1][c]
    float* wfT = smem;                   // [64][65] transposed W_fuse top half
    for (int ch = t; ch < 4096; ch += 256) {
      int d0 = ch >> 6, d1 = ch & 63;
      wfT[d1 * 65 + d0] = W_fuse[ch];
    }
    __syncthreads();
    long idx = (long)(id - 1792) * 256 + t;
    int c = (int)(idx >> 10), hd0 = (int)(idx & 1023);
    int h = hd0 >> 6, d0 = hd0 & 63;
    float acc = 0.f;
    for (int d1 = 0; d1 < 64; ++d1)
      acc += wfT[d1 * 65 + d0] * W_proj[(long)(h * 64 + d1) * 1024 + c];
    WcombT[(long)c * 1024 + hd0] = f2b(acc);
  } else {                               // conv_h: h = irfft(exp(-j*alpha), n=2048)
    int tt = id - 5888;
    float a = alpha[0];
    const float wph = 3.14159265358979323846f / 1024.f;
    float acc = 0.f;
    for (int j = 1 + t; j < 1024; j += 256) {
      int ph = (j * tt) & 2047;
      acc += 2.f * __expf(-a * (float)j) * __cosf((float)ph * wph);
    }
    if (t == 0) {
      acc += 1.0f;
      int ph = (1024 * tt) & 2047;
      acc += __expf(-a * 1024.f) * __cosf((float)ph * wph);
    }
    float* red = smem;
    red[t] = acc;
    __syncthreads();
    for (int s = 128; s > 0; s >>= 1) {
      if (t < s) red[t] += red[t + s];
      __syncthreads();
    }
    if (t == 0) hbuf[tt] = red[0] * (1.f / 2048.f);
  }
}

// ---------------- Hb fill ----------------
__global__ void hb_k(const float* __restrict__ hbuf, u16* __restrict__ Hb) {
  long idx0 = ((long)blockIdx.x * 256 + threadIdx.x) * 16;
  int tt = (int)(idx0 >> 11), u0 = (int)(idx0 & 2047);
  u16x4 o;
#pragma unroll
  for (int g = 0; g < 4; ++g) {
#pragma unroll
    for (int e = 0; e < 4; ++e)
      o[e] = f2b(hbuf[(tt - (u0 + g * 4 + e)) & 2047]);
    *(u16x4*)(Hb + idx0 + g * 4) = o;
  }
}

// ---------------- shared bf16 MFMA GEMM body (32x32x16): C = A[M,K] @ Bt[N,K]^T ----------------
// 128x128 tile, BK=64, 4 waves, global_load_lds staging, swizzled LDS.
// C/D: col = lane&31, row = (reg&3) + 8*(reg>>2) + 4*(lane>>5)  [m74/m101-verified]
// bias_mode: 0 none, 1 bias[col], 2 bias[(row>>11)*ldc+col], 3 bias[row]
__device__ __forceinline__ void gemm_body(
    const u16* __restrict__ Ab, int lda, const u16* __restrict__ Bb, int ldb,
    void* __restrict__ Cv, long coff, int ldc, int K, int m0, int n0,
    int bias_mode, const float* __restrict__ bias, bool out_f32,
    u16* As, u16* Bs) {
  const int t = threadIdx.x;
  const int w = t >> 6, l = t & 63;
  const int wr = (w >> 1) * 64, wc = (w & 1) * 64;
  const int lr32 = l & 31, lh = l >> 5;

  f32x16 acc[2][2] = {};

  for (int k0 = 0; k0 < K; k0 += 64) {
    __syncthreads();
#pragma unroll
    for (int q = 0; q < 4; ++q) {
      int ch = (w * 4 + q) * 64 + l;       // linear 16B-chunk index
      int row = ch >> 3;
      int cg = (ch & 7) ^ (row & 7);       // inverse-swizzled source column
      gload_lds16(Ab + (long)(m0 + row) * lda + k0 + cg * 8, &As[(w * 4 + q) * 512]);
      gload_lds16(Bb + (long)(n0 + row) * ldb + k0 + cg * 8, &Bs[(w * 4 + q) * 512]);
    }
    __syncthreads();
#pragma unroll
    for (int kk = 0; kk < 4; ++kk) {       // 4 K-substeps of 16
      bf16x8 af[2], bfr[2];
#pragma unroll
      for (int i = 0; i < 2; ++i) {
        int ar = wr + i * 32 + lr32;
        af[i] = *(const bf16x8*)&As[ar * 64 + ((((kk << 1) | lh) ^ (ar & 7)) << 3)];
        int br = wc + i * 32 + lr32;
        bfr[i] = *(const bf16x8*)&Bs[br * 64 + ((((kk << 1) | lh) ^ (br & 7)) << 3)];
      }
#pragma unroll
      for (int i = 0; i < 2; ++i)
#pragma unroll
        for (int j = 0; j < 2; ++j)
          acc[i][j] = __builtin_amdgcn_mfma_f32_32x32x16_bf16(af[i], bfr[j], acc[i][j], 0, 0, 0);
    }
  }

#pragma unroll
  for (int i = 0; i < 2; ++i)
#pragma unroll
    for (int j = 0; j < 2; ++j)
#pragma unroll
      for (int reg = 0; reg < 16; ++reg) {
        int row = m0 + wr + i * 32 + (reg & 3) + 8 * (reg >> 2) + 4 * lh;
        int col = n0 + wc + j * 32 + lr32;
        float v = acc[i][j][reg];
        if (bias_mode == 1) v += bias[col];
        else if (bias_mode == 2) v += bias[(row >> 11) * ldc + col];
        else if (bias_mode == 3) v += bias[row];
        if (out_f32)
          ((float*)Cv)[coff + (long)row * ldc + col] = v;
        else
          ((u16*)Cv)[coff + (long)row * ldc + col] = f2b(v);
      }
}

// phase 1: Gx (xm = Hb @ x[b], ids [0,256)) + vT (Wv @ xb[b]^T, ids [256,512))
__global__ __launch_bounds__(256)
void phase1_k(const u16* __restrict__ Hb, const u16* __restrict__ xT,
              const u16* __restrict__ xb, const u16* __restrict__ WaT,
              const float* __restrict__ b_attn,
              u16* __restrict__ xm, u16* __restrict__ vT) {
  __shared__ u16 As[128 * 64];
  __shared__ u16 Bs[128 * 64];
  const int id = blockIdx.x;
  if (id < 256) {   // Gx: xm[z][tt][c] = sum_u Hb[tt][u] x[z][u][c]
    int z = id >> 7, r = id & 127;           // 16 m-tiles x 8 n-tiles
    gemm_body(Hb, 2048, xT + (long)z * 1024 * 2048, 2048,
              (void*)xm, (long)z * 2048 * 1024, 1024, 2048,
              (r >> 3) * 128, (r & 7) * 128, 0, nullptr, false, As, Bs);
  } else {          // vT[z][c][t] = sum_k Wv[c][k] xb[z][t][k] + b_v[c]
    int id2 = id - 256;
    int z = id2 >> 7, r = id2 & 127;         // 8 m-tiles x 16 n-tiles
    gemm_body(WaT + (long)2048 * 1024, 1024, xb + (long)z * 2048 * 1024, 1024,
              (void*)vT, (long)z * 1024 * 2048, 2048, 1024,
              (r >> 4) * 128, (r & 15) * 128, 3, b_attn + 2048, false, As, Bs);
  }
}

// G1b: qkm2 = xm @ W_qk + b_qk  (grid (16,33); y==32 row does vT row-sums)
__global__ __launch_bounds__(256)
void g1b_k(const u16* __restrict__ xm, const u16* __restrict__ WaT,
           const float* __restrict__ b_attn, const u16* __restrict__ vT,
           u16* __restrict__ qkm2, float* __restrict__ part) {
  __shared__ u16 As[128 * 64];
  __shared__ u16 Bs[128 * 64];
  if (blockIdx.y == 32) {    // vmean partial: full row sums of vT (rows = b*1024+c)
    int row = blockIdx.x * 128 + (threadIdx.x >> 1);
    int half = threadIdx.x & 1;
    const bf16x8* src = (const bf16x8*)(vT + (long)row * 2048 + half * 1024);
    float s = 0.f;
    for (int i = 0; i < 128; ++i) {
      bf16x8 v = src[i];
#pragma unroll
      for (int k = 0; k < 8; ++k) s += b2f((u16)(unsigned short)v[k]);
    }
    s += __shfl_xor(s, 1);
    if (half == 0) part[row] = s;
    return;
  }
  gemm_body(xm, 1024, WaT, 1024, (void*)qkm2, 0L, 2048, 1024,
            blockIdx.y * 128, blockIdx.x * 128, 1, b_attn, false, As, Bs);
}

// G3: out = localf @ WcombT^T + out_const[b]
__global__ __launch_bounds__(256)
void g3_k(const u16* __restrict__ localf, const u16* __restrict__ WcombT,
          const float* __restrict__ out_const, float* __restrict__ out) {
  __shared__ u16 As[128 * 64];
  __shared__ u16 Bs[128 * 64];
  gemm_body(localf, 1024, WcombT, 1024, (void*)out, 0L, 1024, 1024,
            blockIdx.y * 128, blockIdx.x * 128, 2, out_const, true, As, Bs);
}

// ---------------- latent chain (standalone): mean->W_lat->W_fuse[64:]->W_proj ----------------
__global__ void latent_k(const float* __restrict__ part, const float* __restrict__ W_lat,
                         const float* __restrict__ b_lat, const float* __restrict__ W_fuse,
                         const float* __restrict__ b_fuse, const float* __restrict__ W_proj,
                         const float* __restrict__ b_proj, float* __restrict__ out_const) {
  const int b = blockIdx.x, t = threadIdx.x;
  const int h = t >> 6, d = t & 63;
  __shared__ float mv[1024], lat[1024];
  mv[t] = part[(long)b * 1024 + t] * (1.f / 2048.f);
  __syncthreads();
  float acc = b_lat[d];
  for (int k = 0; k < 64; ++k) acc += mv[h * 64 + k] * W_lat[k * 64 + d];
  lat[t] = acc;
  __syncthreads();
  float acc2 = b_fuse[d];
  for (int k = 0; k < 64; ++k) acc2 += lat[h * 64 + k] * W_fuse[(64 + k) * 64 + d];
  __syncthreads();
  mv[t] = acc2;                           // lat_term
  __syncthreads();
  float acc3 = b_proj[t];
  for (int hd = 0; hd < 1024; ++hd) acc3 += mv[hd] * W_proj[(long)hd * 1024 + t];
  out_const[b * 1024 + t] = acc3;
}

// ---------------- flash attention (R11 schedule; rel loads hoisted to loop top) ----------------
// grid (B, H, T/128); 256 thr, 4 waves; each wave owns 32 Q rows.
// rel added unconditionally (exact when zero); loads issued before QK^T so their
// latency hides under the MFMAs + staging issue (consumed pre-barrier, no
// cross-barrier live range).
__global__ __launch_bounds__(256)
void fa_k(const u16* __restrict__ qkm2, const u16* __restrict__ vT,
          const float* __restrict__ rel, u16* __restrict__ localf) {
  const int b = blockIdx.x, h = blockIdx.y;
  const int t0 = blockIdx.z * 128;
  const int t = threadIdx.x, w = t >> 6, l = t & 63;
  const int lrow = l & 15, lk = l >> 4;
  __shared__ u16 QPs[9216];      // Q staging (8192 u16), then per-wave P [32][72]
  __shared__ u16 Ks[2][64 * 64];
  __shared__ u16 Vs[2][64 * 64];

  const u16* qm = qkm2 + (long)b * 2048 * 2048;
  const u16* km = qm + 1024;
  const float* relp = rel + ((long)h * 2048 + t0 + w * 32 + lk * 4) * 2048 + lrow;

#pragma unroll
  for (int q = 0; q < 4; ++q) {
    int ch = (w * 4 + q) * 64 + l;
    int r = ch >> 3;
    int cg = (ch & 7) ^ (r & 7);
    gload_lds16(qm + (long)(t0 + r) * 2048 + h * 64 + cg * 8, &QPs[(w * 4 + q) * 512]);
  }
  auto stage = [&](int tile, int buf) {
    int s0 = tile * 64;
#pragma unroll
    for (int q = 0; q < 2; ++q) {
      int ch = (w * 2 + q) * 64 + l;
      int r = ch >> 3;
      int cg = (ch & 7) ^ (r & 7);
      gload_lds16(km + (long)(s0 + r) * 2048 + h * 64 + cg * 8,
                  &Ks[buf][(w * 2 + q) * 512]);
      gload_lds16(vT + ((long)b * 1024 + h * 64 + r) * 2048 + s0 + cg * 8,
                  &Vs[buf][(w * 2 + q) * 512]);
    }
  };
  stage(0, 0);
  __syncthreads();

  bf16x8 qf[2][2];
#pragma unroll
  for (int i = 0; i < 2; ++i)
#pragma unroll
    for (int kk = 0; kk < 2; ++kk) {
      int r = w * 32 + i * 16 + lrow;
      qf[i][kk] = *(const bf16x8*)&QPs[r * 64 + ((((kk << 2) | lk) ^ (r & 7)) << 3)];
    }
  __syncthreads();  // all waves done reading Q before any P store into QPs

  u16* Pw = QPs + w * 2304 + (lk * 4) * 72 + lrow;       // write base
  const u16* Pr = QPs + w * 2304 + lrow * 72 + lk * 8;   // read base

  f32x4 o[2][4] = {};
  float lsum[2][4] = {};

  for (int it = 0; it < 32; ++it) {
    const int cur = it & 1;
    const u16* Kb = Ks[cur];
    const u16* Vb = Vs[cur];

    // rel tile loads FIRST: independent stream, latency hides under QK^T + stage
    float rl[2][4][4];
#pragma unroll
    for (int i = 0; i < 2; ++i)
#pragma unroll
      for (int r = 0; r < 4; ++r)
#pragma unroll
        for (int j = 0; j < 4; ++j)
          rl[i][r][j] = relp[(long)(i * 16 + r) * 2048 + it * 64 + j * 16];

    // QK^T
    f32x4 sa[2][4] = {};
#pragma unroll
    for (int kk = 0; kk < 2; ++kk) {
      bf16x8 kf[4];
#pragma unroll
      for (int j = 0; j < 4; ++j) {
        int r = j * 16 + lrow;
        kf[j] = *(const bf16x8*)&Kb[r * 64 + ((((kk << 2) | lk) ^ (r & 7)) << 3)];
      }
#pragma unroll
      for (int i = 0; i < 2; ++i)
#pragma unroll
        for (int j = 0; j < 4; ++j)
          sa[i][j] = __builtin_amdgcn_mfma_f32_16x16x32_bf16(qf[i][kk], kf[j], sa[i][j], 0, 0, 0);
    }

    if (it < 31) stage(it + 1, cur ^ 1);   // K/V prefetch (async -> LDS)

#pragma unroll
    for (int i = 0; i < 2; ++i)
#pragma unroll
      for (int j = 0; j < 4; ++j)
#pragma unroll
        for (int r = 0; r < 4; ++r) {
          float vv = sa[i][j][r] * 0.1803368867f      // 0.125 * log2(e)
                     + 1.4426950409f * rl[i][r][j];
          float p = exp2f(fminf(vv, 86.0f));
          lsum[i][r] += p;
          Pw[i * 1152 + r * 72 + j * 16] = f2b(p);
        }

#pragma unroll
    for (int kk = 0; kk < 2; ++kk) {
      bf16x8 pf[2], vf[4];
#pragma unroll
      for (int i = 0; i < 2; ++i)
        pf[i] = *(const bf16x8*)&Pr[i * 1152 + kk * 32];
#pragma unroll
      for (int j = 0; j < 4; ++j) {
        int r = j * 16 + lrow;
        vf[j] = *(const bf16x8*)&Vb[r * 64 + ((((kk << 2) | lk) ^ (r & 7)) << 3)];
      }
#pragma unroll
      for (int i = 0; i < 2; ++i)
#pragma unroll
        for (int j = 0; j < 4; ++j)
          o[i][j] = __builtin_amdgcn_mfma_f32_16x16x32_bf16(pf[i], vf[j], o[i][j], 0, 0, 0);
    }
    __syncthreads();
  }

#pragma unroll
  for (int i = 0; i < 2; ++i)
#pragma unroll
    for (int r = 0; r < 4; ++r) {
      float s = lsum[i][r];
      s += __shfl_xor(s, 1);
      s += __shfl_xor(s, 2);
      s += __shfl_xor(s, 4);
      s += __shfl_xor(s, 8);
      float inv = 1.0f / s;
#pragma unroll
      for (int j = 0; j < 4; ++j)
        localf[((long)b * 2048 + t0 + w * 32 + i * 16 + lk * 4 + r) * 1024
               + h * 64 + j * 16 + lrow] = f2b(o[i][j][r] * inv);
    }
}

// ---------------- launch ----------------
extern "C" void kernel_launch(void* const* d_in, const int* in_sizes, int n_in,
                              void* d_out, int out_size, void* d_ws, size_t ws_size,
                              hipStream_t stream) {
  (void)in_sizes; (void)n_in; (void)out_size; (void)ws_size;
  const float* x      = (const float*)d_in[0];
  const float* W_attn = (const float*)d_in[1];
  const float* b_attn = (const float*)d_in[2];
  const float* W_proj = (const float*)d_in[3];
  const float* b_proj = (const float*)d_in[4];
  const float* rel    = (const float*)d_in[5];
  const float* alpha  = (const float*)d_in[6];
  const float* W_lat  = (const float*)d_in[7];
  const float* b_lat  = (const float*)d_in[8];
  const float* W_fuse = (const float*)d_in[9];
  const float* b_fuse = (const float*)d_in[10];
  float* out = (float*)d_out;
  char* ws = (char*)d_ws;
  const size_t MiB = 1048576;

  u16*   xb       = (u16*)(ws + 0 * MiB);    // [4096][1024] bf16
  u16*   xT       = (u16*)(ws + 8 * MiB);    // [2][1024][2048] bf16
  u16*   WaT      = (u16*)(ws + 16 * MiB);   // [3072][1024] bf16
  u16*   Hb       = (u16*)(ws + 22 * MiB);   // [2048][2048] bf16
  u16*   xm       = (u16*)(ws + 30 * MiB);   // [2][2048][1024] bf16 (= H x)
  u16*   qkm2     = (u16*)(ws + 46 * MiB);   // [4096][2048] bf16 (q|k modulated)
  u16*   vT       = (u16*)(ws + 62 * MiB);   // [2][1024][2048] bf16
  u16*   localf   = (u16*)(ws + 70 * MiB);   // [4096][1024] bf16
  u16*   WcombT   = (u16*)(ws + 78 * MiB);   // [1024][1024] bf16
  float* hbuf     = (float*)(ws + 80 * MiB);
  float* out_const= (float*)(ws + 80 * MiB + 16384);
  float* part     = (float*)(ws + 80 * MiB + 65536);  // [2048] f32 row sums

  // 1. prep: WaT, xT+xb (one pass over x), WcombT (gather-fixed), conv_h
  prep_k<<<7936, 256, 0, stream>>>(x, W_attn, W_fuse, W_proj, alpha,
                                   xb, WaT, xT, WcombT, hbuf);
  // 2. Hb fill
  hb_k<<<1024, 256, 0, stream>>>(hbuf, Hb);

  // 3. phase1: Gx (xm) + vT GEMMs, 512 blocks
  phase1_k<<<512, 256, 0, stream>>>(Hb, xT, xb, WaT, b_attn, xm, vT);

  // 4. G1b: qkm2 = xm @ W_qk + b_qk; plus vT row-sum partials (y==32)
  g1b_k<<<dim3(16, 33), 256, 0, stream>>>(xm, WaT, b_attn, vT, qkm2, part);

  // 5. latent chain -> out_const
  latent_k<<<2, 1024, 0, stream>>>(part, W_lat, b_lat, W_fuse, b_fuse,
                                   W_proj, b_proj, out_const);

  // 6. flash attention (rel hoisted to loop top) -> localf
  fa_k<<<dim3(2, 16, 16), 256, 0, stream>>>(qkm2, vT, rel, localf);

  // 7. G3: out = localf @ WcombT^T + out_const[b]
  g3_k<<<dim3(8, 32), 256, 0, stream>>>(localf, WcombT, out_const, out);
}

// Round 18
// 283.197 us; speedup vs baseline: 1.2059x; 1.0186x over previous
//
#include <hip/hip_runtime.h>

typedef unsigned short u16;
typedef __attribute__((ext_vector_type(8))) short bf16x8;
typedef __attribute__((ext_vector_type(4))) float f32x4;
typedef __attribute__((ext_vector_type(16))) float f32x16;
typedef __attribute__((ext_vector_type(4))) unsigned short u16x4;

__device__ __forceinline__ u16 f2b(float f) {
  union { float f; unsigned u; } x; x.f = f;
  unsigned u = x.u;
  return (u16)((u + 0x7fffu + ((u >> 16) & 1u)) >> 16);
}
__device__ __forceinline__ float b2f(u16 b) {
  union { unsigned u; float f; } x; x.u = ((unsigned)b) << 16;
  return x.f;
}

// async global->LDS, 16B per lane; lds base must be wave-uniform.
__device__ __forceinline__ void gload_lds16(const void* g, void* l) {
  __builtin_amdgcn_global_load_lds(
      (const __attribute__((address_space(1))) void*)g,
      (__attribute__((address_space(3))) void*)l, 16, 0, 0);
}

// bijective XCD swizzle for n % 8 == 0 block counts: consecutive tiles land on
// the same XCD's L2 so shared A/B panels are fetched once per XCD, not 8x.
__device__ __forceinline__ int xcd_swz(int lid, int n) {
  return (lid & 7) * (n >> 3) + (lid >> 3);
}

// ---------------- fused prep ----------------
// [0,768): W_attn->WaT; [768,1792): x->xT AND x->xb (one pass);
// [1792,5888): WcombT (LDS-transposed W_fuse); [5888,7936): conv_h.
__device__ __forceinline__ void tr_f2b_body(const float* __restrict__ in,
                                            u16* __restrict__ out, int R, int C,
                                            int bx, int by, int t, float* tile) {
  int r0 = by * 64, c0 = bx * 64;
  for (int ch = t; ch < 1024; ch += 256) {
    int r = ch >> 4, q = ch & 15;
    float4 v = *(const float4*)(in + (long)(r0 + r) * C + c0 + q * 4);
    tile[r * 65 + q * 4 + 0] = v.x; tile[r * 65 + q * 4 + 1] = v.y;
    tile[r * 65 + q * 4 + 2] = v.z; tile[r * 65 + q * 4 + 3] = v.w;
  }
  __syncthreads();
  for (int ch = t; ch < 1024; ch += 256) {
    int cc = ch >> 4, g = ch & 15;
    u16x4 o;
    o[0] = f2b(tile[(g * 4 + 0) * 65 + cc]); o[1] = f2b(tile[(g * 4 + 1) * 65 + cc]);
    o[2] = f2b(tile[(g * 4 + 2) * 65 + cc]); o[3] = f2b(tile[(g * 4 + 3) * 65 + cc]);
    *(u16x4*)(out + (long)(c0 + cc) * R + r0 + g * 4) = o;
  }
}

__global__ void prep_k(const float* __restrict__ x, const float* __restrict__ W_attn,
                       const float* __restrict__ W_fuse, const float* __restrict__ W_proj,
                       const float* __restrict__ alpha,
                       u16* __restrict__ xb, u16* __restrict__ WaT, u16* __restrict__ xT,
                       u16* __restrict__ WcombT, float* __restrict__ hbuf) {
  __shared__ float smem[64 * 65];
  const int id = blockIdx.x, t = threadIdx.x;
  if (id < 768) {                        // W_attn[1024][3072] -> WaT[3072][1024]
    tr_f2b_body(W_attn, WaT, 1024, 3072, id % 48, id / 48, t, smem);
  } else if (id < 1792) {                // x -> xT (transpose) AND xb (cvt), one pass
    int local = id - 768;
    int bx = local & 15, by = (local >> 4) & 31, z = local >> 9;
    const float* src = x + (long)z * 2048 * 1024;
    u16* xbz = xb + (long)z * 2048 * 1024;
    u16* xTz = xT + (long)z * 1024 * 2048;
    int r0 = by * 64, c0 = bx * 64;
    for (int ch = t; ch < 1024; ch += 256) {
      int r = ch >> 4, q = ch & 15;
      float4 v = *(const float4*)(src + (long)(r0 + r) * 1024 + c0 + q * 4);
      smem[r * 65 + q * 4 + 0] = v.x; smem[r * 65 + q * 4 + 1] = v.y;
      smem[r * 65 + q * 4 + 2] = v.z; smem[r * 65 + q * 4 + 3] = v.w;
      u16x4 o;
      o[0] = f2b(v.x); o[1] = f2b(v.y); o[2] = f2b(v.z); o[3] = f2b(v.w);
      *(u16x4*)(xbz + (long)(r0 + r) * 1024 + c0 + q * 4) = o;
    }
    __syncthreads();
    for (int ch = t; ch < 1024; ch += 256) {
      int cc = ch >> 4, g = ch & 15;
      u16x4 o;
      o[0] = f2b(smem[(g * 4 + 0) * 65 + cc]); o[1] = f2b(smem[(g * 4 + 1) * 65 + cc]);
      o[2] = f2b(smem[(g * 4 + 2) * 65 + cc]); o[3] = f2b(smem[(g * 4 + 3) * 65 + cc]);
      *(u16x4*)(xTz + (long)(c0 + cc) * 2048 + r0 + g * 4) = o;
    }
  } else if (id < 5888) {                // WcombT[c][hd0] = sum_d1 Wf[d0][d1] Wp[h*64+d1][c]
    float* wfT = smem;                   // [64][65] transposed W_fuse top half
    for (int ch = t; ch < 4096; ch += 256) {
      int d0 = ch >> 6, d1 = ch & 63;
      wfT[d1 * 65 + d0] = W_fuse[ch];
    }
    __syncthreads();
    long idx = (long)(id - 1792) * 256 + t;
    int c = (int)(idx >> 10), hd0 = (int)(idx & 1023);
    int h = hd0 >> 6, d0 = hd0 & 63;
    float acc = 0.f;
    for (int d1 = 0; d1 < 64; ++d1)
      acc += wfT[d1 * 65 + d0] * W_proj[(long)(h * 64 + d1) * 1024 + c];
    WcombT[(long)c * 1024 + hd0] = f2b(acc);
  } else {                               // conv_h: h = irfft(exp(-j*alpha), n=2048)
    int tt = id - 5888;
    float a = alpha[0];
    const float wph = 3.14159265358979323846f / 1024.f;
    float acc = 0.f;
    for (int j = 1 + t; j < 1024; j += 256) {
      int ph = (j * tt) & 2047;
      acc += 2.f * __expf(-a * (float)j) * __cosf((float)ph * wph);
    }
    if (t == 0) {
      acc += 1.0f;
      int ph = (1024 * tt) & 2047;
      acc += __expf(-a * 1024.f) * __cosf((float)ph * wph);
    }
    float* red = smem;
    red[t] = acc;
    __syncthreads();
    for (int s = 128; s > 0; s >>= 1) {
      if (t < s) red[t] += red[t + s];
      __syncthreads();
    }
    if (t == 0) hbuf[tt] = red[0] * (1.f / 2048.f);
  }
}

// ---------------- Hb fill ----------------
__global__ void hb_k(const float* __restrict__ hbuf, u16* __restrict__ Hb) {
  long idx0 = ((long)blockIdx.x * 256 + threadIdx.x) * 16;
  int tt = (int)(idx0 >> 11), u0 = (int)(idx0 & 2047);
  u16x4 o;
#pragma unroll
  for (int g = 0; g < 4; ++g) {
#pragma unroll
    for (int e = 0; e < 4; ++e)
      o[e] = f2b(hbuf[(tt - (u0 + g * 4 + e)) & 2047]);
    *(u16x4*)(Hb + idx0 + g * 4) = o;
  }
}

// ---------------- shared bf16 MFMA GEMM body (32x32x16): C = A[M,K] @ Bt[N,K]^T ----------------
// 128x128 tile, BK=64, 4 waves, global_load_lds staging, swizzled LDS.
// C/D: col = lane&31, row = (reg&3) + 8*(reg>>2) + 4*(lane>>5)  [m74/m101-verified]
// bias_mode: 0 none, 1 bias[col], 2 bias[(row>>11)*ldc+col], 3 bias[row]
__device__ __forceinline__ void gemm_body(
    const u16* __restrict__ Ab, int lda, const u16* __restrict__ Bb, int ldb,
    void* __restrict__ Cv, long coff, int ldc, int K, int m0, int n0,
    int bias_mode, const float* __restrict__ bias, bool out_f32,
    u16* As, u16* Bs) {
  const int t = threadIdx.x;
  const int w = t >> 6, l = t & 63;
  const int wr = (w >> 1) * 64, wc = (w & 1) * 64;
  const int lr32 = l & 31, lh = l >> 5;

  f32x16 acc[2][2] = {};

  for (int k0 = 0; k0 < K; k0 += 64) {
    __syncthreads();
#pragma unroll
    for (int q = 0; q < 4; ++q) {
      int ch = (w * 4 + q) * 64 + l;       // linear 16B-chunk index
      int row = ch >> 3;
      int cg = (ch & 7) ^ (row & 7);       // inverse-swizzled source column
      gload_lds16(Ab + (long)(m0 + row) * lda + k0 + cg * 8, &As[(w * 4 + q) * 512]);
      gload_lds16(Bb + (long)(n0 + row) * ldb + k0 + cg * 8, &Bs[(w * 4 + q) * 512]);
    }
    __syncthreads();
#pragma unroll
    for (int kk = 0; kk < 4; ++kk) {       // 4 K-substeps of 16
      bf16x8 af[2], bfr[2];
#pragma unroll
      for (int i = 0; i < 2; ++i) {
        int ar = wr + i * 32 + lr32;
        af[i] = *(const bf16x8*)&As[ar * 64 + ((((kk << 1) | lh) ^ (ar & 7)) << 3)];
        int br = wc + i * 32 + lr32;
        bfr[i] = *(const bf16x8*)&Bs[br * 64 + ((((kk << 1) | lh) ^ (br & 7)) << 3)];
      }
#pragma unroll
      for (int i = 0; i < 2; ++i)
#pragma unroll
        for (int j = 0; j < 2; ++j)
          acc[i][j] = __builtin_amdgcn_mfma_f32_32x32x16_bf16(af[i], bfr[j], acc[i][j], 0, 0, 0);
    }
  }

#pragma unroll
  for (int i = 0; i < 2; ++i)
#pragma unroll
    for (int j = 0; j < 2; ++j)
#pragma unroll
      for (int reg = 0; reg < 16; ++reg) {
        int row = m0 + wr + i * 32 + (reg & 3) + 8 * (reg >> 2) + 4 * lh;
        int col = n0 + wc + j * 32 + lr32;
        float v = acc[i][j][reg];
        if (bias_mode == 1) v += bias[col];
        else if (bias_mode == 2) v += bias[(row >> 11) * ldc + col];
        else if (bias_mode == 3) v += bias[row];
        if (out_f32)
          ((float*)Cv)[coff + (long)row * ldc + col] = v;
        else
          ((u16*)Cv)[coff + (long)row * ldc + col] = f2b(v);
      }
}

// phase 1: Gx (xm = Hb @ x[b], ids [0,256)) + vT (Wv @ xb[b]^T, ids [256,512))
// Tile ids XCD-swizzled within each sub-GEMM (256 % 8 == 0).
__global__ __launch_bounds__(256)
void phase1_k(const u16* __restrict__ Hb, const u16* __restrict__ xT,
              const u16* __restrict__ xb, const u16* __restrict__ WaT,
              const float* __restrict__ b_attn,
              u16* __restrict__ xm, u16* __restrict__ vT) {
  __shared__ u16 As[128 * 64];
  __shared__ u16 Bs[128 * 64];
  const int id = blockIdx.x;
  if (id < 256) {   // Gx: xm[z][tt][c] = sum_u Hb[tt][u] x[z][u][c]
    int r2 = xcd_swz(id, 256);
    int z = r2 >> 7, r = r2 & 127;           // 16 m-tiles x 8 n-tiles
    gemm_body(Hb, 2048, xT + (long)z * 1024 * 2048, 2048,
              (void*)xm, (long)z * 2048 * 1024, 1024, 2048,
              (r >> 3) * 128, (r & 7) * 128, 0, nullptr, false, As, Bs);
  } else {          // vT[z][c][t] = sum_k Wv[c][k] xb[z][t][k] + b_v[c]
    int r2 = xcd_swz(id - 256, 256);
    int z = r2 >> 7, r = r2 & 127;           // 8 m-tiles x 16 n-tiles
    gemm_body(WaT + (long)2048 * 1024, 1024, xb + (long)z * 2048 * 1024, 1024,
              (void*)vT, (long)z * 1024 * 2048, 2048, 1024,
              (r >> 4) * 128, (r & 15) * 128, 3, b_attn + 2048, false, As, Bs);
  }
}

// G1b: qkm2 = xm @ W_qk + b_qk  (grid (16,33); y==32 row does vT row-sums)
// GEMM tile ids (512) XCD-swizzled.
__global__ __launch_bounds__(256)
void g1b_k(const u16* __restrict__ xm, const u16* __restrict__ WaT,
           const float* __restrict__ b_attn, const u16* __restrict__ vT,
           u16* __restrict__ qkm2, float* __restrict__ part) {
  __shared__ u16 As[128 * 64];
  __shared__ u16 Bs[128 * 64];
  if (blockIdx.y == 32) {    // vmean partial: full row sums of vT (rows = b*1024+c)
    int row = blockIdx.x * 128 + (threadIdx.x >> 1);
    int half = threadIdx.x & 1;
    const bf16x8* src = (const bf16x8*)(vT + (long)row * 2048 + half * 1024);
    float s = 0.f;
    for (int i = 0; i < 128; ++i) {
      bf16x8 v = src[i];
#pragma unroll
      for (int k = 0; k < 8; ++k) s += b2f((u16)(unsigned short)v[k]);
    }
    s += __shfl_xor(s, 1);
    if (half == 0) part[row] = s;
    return;
  }
  int lid = xcd_swz(blockIdx.y * 16 + blockIdx.x, 512);
  int my = lid >> 4, mx = lid & 15;
  gemm_body(xm, 1024, WaT, 1024, (void*)qkm2, 0L, 2048, 1024,
            my * 128, mx * 128, 1, b_attn, false, As, Bs);
}

// G3: out = localf @ WcombT^T + out_const[b]  (256 tiles, XCD-swizzled)
__global__ __launch_bounds__(256)
void g3_k(const u16* __restrict__ localf, const u16* __restrict__ WcombT,
          const float* __restrict__ out_const, float* __restrict__ out) {
  __shared__ u16 As[128 * 64];
  __shared__ u16 Bs[128 * 64];
  int lid = xcd_swz(blockIdx.y * 8 + blockIdx.x, 256);
  int my = lid >> 3, mx = lid & 7;
  gemm_body(localf, 1024, WcombT, 1024, (void*)out, 0L, 1024, 1024,
            my * 128, mx * 128, 2, out_const, true, As, Bs);
}

// ---------------- latent chain (standalone): mean->W_lat->W_fuse[64:]->W_proj ----------------
__global__ void latent_k(const float* __restrict__ part, const float* __restrict__ W_lat,
                         const float* __restrict__ b_lat, const float* __restrict__ W_fuse,
                         const float* __restrict__ b_fuse, const float* __restrict__ W_proj,
                         const float* __restrict__ b_proj, float* __restrict__ out_const) {
  const int b = blockIdx.x, t = threadIdx.x;
  const int h = t >> 6, d = t & 63;
  __shared__ float mv[1024], lat[1024];
  mv[t] = part[(long)b * 1024 + t] * (1.f / 2048.f);
  __syncthreads();
  float acc = b_lat[d];
  for (int k = 0; k < 64; ++k) acc += mv[h * 64 + k] * W_lat[k * 64 + d];
  lat[t] = acc;
  __syncthreads();
  float acc2 = b_fuse[d];
  for (int k = 0; k < 64; ++k) acc2 += lat[h * 64 + k] * W_fuse[(64 + k) * 64 + d];
  __syncthreads();
  mv[t] = acc2;                           // lat_term
  __syncthreads();
  float acc3 = b_proj[t];
  for (int hd = 0; hd < 1024; ++hd) acc3 += mv[hd] * W_proj[(long)hd * 1024 + t];
  out_const[b * 1024 + t] = acc3;
}

// ---------------- flash attention (R11 schedule; rel loads at loop top) ----------------
// grid (B, H, T/128); 256 thr, 4 waves; each wave owns 32 Q rows.
// rel added unconditionally (exact when zero).
__global__ __launch_bounds__(256)
void fa_k(const u16* __restrict__ qkm2, const u16* __restrict__ vT,
          const float* __restrict__ rel, u16* __restrict__ localf) {
  const int b = blockIdx.x, h = blockIdx.y;
  const int t0 = blockIdx.z * 128;
  const int t = threadIdx.x, w = t >> 6, l = t & 63;
  const int lrow = l & 15, lk = l >> 4;
  __shared__ u16 QPs[9216];      // Q staging (8192 u16), then per-wave P [32][72]
  __shared__ u16 Ks[2][64 * 64];
  __shared__ u16 Vs[2][64 * 64];

  const u16* qm = qkm2 + (long)b * 2048 * 2048;
  const u16* km = qm + 1024;
  const float* relp = rel + ((long)h * 2048 + t0 + w * 32 + lk * 4) * 2048 + lrow;

#pragma unroll
  for (int q = 0; q < 4; ++q) {
    int ch = (w * 4 + q) * 64 + l;
    int r = ch >> 3;
    int cg = (ch & 7) ^ (r & 7);
    gload_lds16(qm + (long)(t0 + r) * 2048 + h * 64 + cg * 8, &QPs[(w * 4 + q) * 512]);
  }
  auto stage = [&](int tile, int buf) {
    int s0 = tile * 64;
#pragma unroll
    for (int q = 0; q < 2; ++q) {
      int ch = (w * 2 + q) * 64 + l;
      int r = ch >> 3;
      int cg = (ch & 7) ^ (r & 7);
      gload_lds16(km + (long)(s0 + r) * 2048 + h * 64 + cg * 8,
                  &Ks[buf][(w * 2 + q) * 512]);
      gload_lds16(vT + ((long)b * 1024 + h * 64 + r) * 2048 + s0 + cg * 8,
                  &Vs[buf][(w * 2 + q) * 512]);
    }
  };
  stage(0, 0);
  __syncthreads();

  bf16x8 qf[2][2];
#pragma unroll
  for (int i = 0; i < 2; ++i)
#pragma unroll
    for (int kk = 0; kk < 2; ++kk) {
      int r = w * 32 + i * 16 + lrow;
      qf[i][kk] = *(const bf16x8*)&QPs[r * 64 + ((((kk << 2) | lk) ^ (r & 7)) << 3)];
    }
  __syncthreads();  // all waves done reading Q before any P store into QPs

  u16* Pw = QPs + w * 2304 + (lk * 4) * 72 + lrow;       // write base
  const u16* Pr = QPs + w * 2304 + lrow * 72 + lk * 8;   // read base

  f32x4 o[2][4] = {};
  float lsum[2][4] = {};

  for (int it = 0; it < 32; ++it) {
    const int cur = it & 1;
    const u16* Kb = Ks[cur];
    const u16* Vb = Vs[cur];

    // rel tile loads first: independent stream, latency hides under QK^T + stage
    float rl[2][4][4];
#pragma unroll
    for (int i = 0; i < 2; ++i)
#pragma unroll
      for (int r = 0; r < 4; ++r)
#pragma unroll
        for (int j = 0; j < 4; ++j)
          rl[i][r][j] = relp[(long)(i * 16 + r) * 2048 + it * 64 + j * 16];

    // QK^T
    f32x4 sa[2][4] = {};
#pragma unroll
    for (int kk = 0; kk < 2; ++kk) {
      bf16x8 kf[4];
#pragma unroll
      for (int j = 0; j < 4; ++j) {
        int r = j * 16 + lrow;
        kf[j] = *(const bf16x8*)&Kb[r * 64 + ((((kk << 2) | lk) ^ (r & 7)) << 3)];
      }
#pragma unroll
      for (int i = 0; i < 2; ++i)
#pragma unroll
        for (int j = 0; j < 4; ++j)
          sa[i][j] = __builtin_amdgcn_mfma_f32_16x16x32_bf16(qf[i][kk], kf[j], sa[i][j], 0, 0, 0);
    }

    if (it < 31) stage(it + 1, cur ^ 1);   // K/V prefetch (async -> LDS)

#pragma unroll
    for (int i = 0; i < 2; ++i)
#pragma unroll
      for (int j = 0; j < 4; ++j)
#pragma unroll
        for (int r = 0; r < 4; ++r) {
          float vv = sa[i][j][r] * 0.1803368867f      // 0.125 * log2(e)
                     + 1.4426950409f * rl[i][r][j];
          float p = exp2f(fminf(vv, 86.0f));
          lsum[i][r] += p;
          Pw[i * 1152 + r * 72 + j * 16] = f2b(p);
        }

#pragma unroll
    for (int kk = 0; kk < 2; ++kk) {
      bf16x8 pf[2], vf[4];
#pragma unroll
      for (int i = 0; i < 2; ++i)
        pf[i] = *(const bf16x8*)&Pr[i * 1152 + kk * 32];
#pragma unroll
      for (int j = 0; j < 4; ++j) {
        int r = j * 16 + lrow;
        vf[j] = *(const bf16x8*)&Vb[r * 64 + ((((kk << 2) | lk) ^ (r & 7)) << 3)];
      }
#pragma unroll
      for (int i = 0; i < 2; ++i)
#pragma unroll
        for (int j = 0; j < 4; ++j)
          o[i][j] = __builtin_amdgcn_mfma_f32_16x16x32_bf16(pf[i], vf[j], o[i][j], 0, 0, 0);
    }
    __syncthreads();
  }

#pragma unroll
  for (int i = 0; i < 2; ++i)
#pragma unroll
    for (int r = 0; r < 4; ++r) {
      float s = lsum[i][r];
      s += __shfl_xor(s, 1);
      s += __shfl_xor(s, 2);
      s += __shfl_xor(s, 4);
      s += __shfl_xor(s, 8);
      float inv = 1.0f / s;
#pragma unroll
      for (int j = 0; j < 4; ++j)
        localf[((long)b * 2048 + t0 + w * 32 + i * 16 + lk * 4 + r) * 1024
               + h * 64 + j * 16 + lrow] = f2b(o[i][j][r] * inv);
    }
}

// ---------------- launch ----------------
extern "C" void kernel_launch(void* const* d_in, const int* in_sizes, int n_in,
                              void* d_out, int out_size, void* d_ws, size_t ws_size,
                              hipStream_t stream) {
  (void)in_sizes; (void)n_in; (void)out_size; (void)ws_size;
  const float* x      = (const float*)d_in[0];
  const float* W_attn = (const float*)d_in[1];
  const float* b_attn = (const float*)d_in[2];
  const float* W_proj = (const float*)d_in[3];
  const float* b_proj = (const float*)d_in[4];
  const float* rel    = (const float*)d_in[5];
  const float* alpha  = (const float*)d_in[6];
  const float* W_lat  = (const float*)d_in[7];
  const float* b_lat  = (const float*)d_in[8];
  const float* W_fuse = (const float*)d_in[9];
  const float* b_fuse = (const float*)d_in[10];
  float* out = (float*)d_out;
  char* ws = (char*)d_ws;
  const size_t MiB = 1048576;

  u16*   xb       = (u16*)(ws + 0 * MiB);    // [4096][1024] bf16
  u16*   xT       = (u16*)(ws + 8 * MiB);    // [2][1024][2048] bf16
  u16*   WaT      = (u16*)(ws + 16 * MiB);   // [3072][1024] bf16
  u16*   Hb       = (u16*)(ws + 22 * MiB);   // [2048][2048] bf16
  u16*   xm       = (u16*)(ws + 30 * MiB);   // [2][2048][1024] bf16 (= H x)
  u16*   qkm2     = (u16*)(ws + 46 * MiB);   // [4096][2048] bf16 (q|k modulated)
  u16*   vT       = (u16*)(ws + 62 * MiB);   // [2][1024][2048] bf16
  u16*   localf   = (u16*)(ws + 70 * MiB);   // [4096][1024] bf16
  u16*   WcombT   = (u16*)(ws + 78 * MiB);   // [1024][1024] bf16
  float* hbuf     = (float*)(ws + 80 * MiB);
  float* out_const= (float*)(ws + 80 * MiB + 16384);
  float* part     = (float*)(ws + 80 * MiB + 65536);  // [2048] f32 row sums

  // 1. prep: WaT, xT+xb (one pass over x), WcombT (gather-fixed), conv_h
  prep_k<<<7936, 256, 0, stream>>>(x, W_attn, W_fuse, W_proj, alpha,
                                   xb, WaT, xT, WcombT, hbuf);
  // 2. Hb fill
  hb_k<<<1024, 256, 0, stream>>>(hbuf, Hb);

  // 3. phase1: Gx (xm) + vT GEMMs, 512 blocks (XCD-swizzled)
  phase1_k<<<512, 256, 0, stream>>>(Hb, xT, xb, WaT, b_attn, xm, vT);

  // 4. G1b: qkm2 = xm @ W_qk + b_qk; plus vT row-sum partials (y==32)
  g1b_k<<<dim3(16, 33), 256, 0, stream>>>(xm, WaT, b_attn, vT, qkm2, part);

  // 5. latent chain -> out_const
  latent_k<<<2, 1024, 0, stream>>>(part, W_lat, b_lat, W_fuse, b_fuse,
                                   W_proj, b_proj, out_const);

  // 6. flash attention -> localf
  fa_k<<<dim3(2, 16, 16), 256, 0, stream>>>(qkm2, vT, rel, localf);

  // 7. G3: out = localf @ WcombT^T + out_const[b] (XCD-swizzled)
  g3_k<<<dim3(8, 32), 256, 0, stream>>>(localf, WcombT, out_const, out);
}